// Round 9
// baseline (468.121 us; speedup 1.0000x reference)
//
#include <hip/hip_runtime.h>
#include <hip/hip_cooperative_groups.h>

namespace cg = cooperative_groups;

// x (16,8,512,512) fp32. Per (b,c) row of 2^18 elems: 1%/99% linear-interp
// quantiles -> th = i1+(i99-i1)*alpha; out = relu(x)*sigmoid(beta/th_new*(|x|-th*mask)).
//
// R9 (= R8 resubmitted; R8 hit GPU-acquisition timeout): ONE cooperative
// kernel, 256 blocks x 1024 threads, phases separated by grid.sync().
// RULE: every __syncthreads() is at block-uniform control flow; per-thread
// predication only around the WORK, never around a barrier.

#define ROWS 128
#define NPR  262144
#define BINS 8192
#define SHIFT 19
#define CAP  4096
#define CBUF 2048
#define TPB  1024
#define NBLK 256

// rank targets: 0.01*262143 = 2621.43 ; 0.99*262143 = 259521.57
#define K_LO 2621u
#define K_HI 259521u

// ws layout (u32 units)
#define OFF_GH   0
#define OFF_GCNT (NBLK*BINS)
#define OFF_SB   (OFF_GCNT + 256)
#define OFF_CAND (OFF_SB + ROWS*8)
#define OFF_QV   (OFF_CAND + ROWS*2*CAP)

typedef float f32x4 __attribute__((ext_vector_type(4)));

__device__ __forceinline__ unsigned keyOf(float f) {
    unsigned u = __float_as_uint(f);
    return (u & 0x80000000u) ? ~u : (u | 0x80000000u);
}
__device__ __forceinline__ float keyToFloat(unsigned k) {
    unsigned u = (k & 0x80000000u) ? (k & 0x7fffffffu) : ~k;
    return __uint_as_float(u);
}

__global__ __launch_bounds__(TPB) void k_fused(const float* __restrict__ x,
                                               const float* __restrict__ alpha,
                                               const float* __restrict__ beta,
                                               unsigned* __restrict__ gh,
                                               unsigned* __restrict__ sbinfo,
                                               unsigned* __restrict__ gcnt,
                                               unsigned* __restrict__ candg,
                                               float* __restrict__ qv,
                                               float* __restrict__ out) {
    cg::grid_group grid = cg::this_grid();
    __shared__ unsigned smem[2 * BINS];   // 64 KB union: hist / cand bufs / keys+sh
    __shared__ unsigned part[256];
    __shared__ unsigned sb[8];
    __shared__ unsigned svar[4];
    __shared__ unsigned lc[2], gbase[2];

    const int bid = blockIdx.x;
    const int tid = threadIdx.x;
    const int row  = bid >> 1;
    const int half = bid & 1;
    const float4* xr = (const float4*)(x + (size_t)row * NPR + (size_t)half * (NPR / 2));
    const int NV = NPR / 2 / 4;   // 32768 float4 per (row-half)

    // ================= P1: histogram =================
    for (int i = tid; i < 2 * BINS; i += TPB) smem[i] = 0;
    __syncthreads();
    {
        unsigned* myh = smem + ((tid >> 9) ? BINS : 0);   // dual sub-hist
        for (int i = tid; i < NV; i += TPB) {
            float4 v = xr[i];
            atomicAdd(&myh[keyOf(v.x) >> SHIFT], 1u);
            atomicAdd(&myh[keyOf(v.y) >> SHIFT], 1u);
            atomicAdd(&myh[keyOf(v.z) >> SHIFT], 1u);
            atomicAdd(&myh[keyOf(v.w) >> SHIFT], 1u);
        }
    }
    __syncthreads();
    {
        unsigned* h = gh + (size_t)bid * BINS;
        for (int i = tid; i < BINS; i += TPB) h[i] = smem[i] + smem[BINS + i];
    }
    grid.sync();

    // ================= P2: scan (blocks 0..127 do work; barriers uniform) ====
    if (bid < ROWS) {                       // block-uniform branch: safe
        const int CH = BINS / 256;          // 32
        unsigned loc[CH];
        const int base = (tid & 255) * CH;
        if (tid < 256) {
            const unsigned* h0 = gh + (size_t)(bid * 2) * BINS;
            const unsigned* h1 = h0 + BINS;
            unsigned s = 0;
            #pragma unroll
            for (int i = 0; i < CH; ++i) { loc[i] = h0[base + i] + h1[base + i]; s += loc[i]; }
            part[tid] = s;
            if (tid < 2) gcnt[bid * 2 + tid] = 0;
        }
        __syncthreads();
        if (tid == 0) {
            unsigned run = 0;
            for (int t = 0; t < 256; ++t) { unsigned tmp = part[t]; part[t] = run; run += tmp; }
        }
        __syncthreads();
        if (tid < 256) {
            unsigned cum = part[tid];
            const unsigned targets[4] = {K_LO, K_LO + 1u, K_HI, K_HI + 1u};
            #pragma unroll
            for (int i = 0; i < CH; ++i) {
                unsigned c = loc[i];
                if (c) {
                    #pragma unroll
                    for (int t = 0; t < 4; ++t) {
                        if (targets[t] >= cum && targets[t] < cum + c) {
                            if      (t == 0) { sb[0] = base + i; sb[2] = cum; }
                            else if (t == 1) { sb[1] = base + i; }
                            else if (t == 2) { sb[3] = base + i; sb[5] = cum; }
                            else             { sb[4] = base + i; }
                        }
                    }
                }
                cum += c;
            }
        }
        __syncthreads();
        if (tid == 0) {
            unsigned* r = sbinfo + bid * 8;
            r[0] = sb[0] << SHIFT;
            r[1] = ((sb[1] + 1u) << SHIFT) - 1u;  // wrap at bin 8191 -> 0xFFFFFFFF ok
            r[2] = sb[2];
            r[3] = sb[3] << SHIFT;
            r[4] = ((sb[4] + 1u) << SHIFT) - 1u;
            r[5] = sb[5];
        }
    }
    grid.sync();

    // ================= P3: collect (2 blocks/row) =================
    {
        unsigned* buf0 = smem;          // 2048
        unsigned* buf1 = smem + CBUF;   // 2048
        if (tid < 2) lc[tid] = 0;
        __syncthreads();
        const unsigned* r = sbinfo + row * 8;
        const unsigned klo0 = r[0], khi0 = r[1], klo1 = r[3], khi1 = r[4];
        for (int i = tid; i < NV; i += TPB) {
            float4 v = xr[i];
            float vv[4] = {v.x, v.y, v.z, v.w};
            #pragma unroll
            for (int j = 0; j < 4; ++j) {
                unsigned key = keyOf(vv[j]);
                if (key >= klo0 && key <= khi0) {
                    unsigned p = atomicAdd(&lc[0], 1u);
                    if (p < CBUF) buf0[p] = key;
                }
                if (key >= klo1 && key <= khi1) {
                    unsigned p = atomicAdd(&lc[1], 1u);
                    if (p < CBUF) buf1[p] = key;
                }
            }
        }
        __syncthreads();
        if (tid < 2) {
            unsigned n = lc[tid]; if (n > CBUF) n = CBUF;
            gbase[tid] = atomicAdd(&gcnt[row * 2 + tid], n);
        }
        __syncthreads();
        unsigned n0 = lc[0] > CBUF ? CBUF : lc[0];
        unsigned n1 = lc[1] > CBUF ? CBUF : lc[1];
        unsigned* c0 = candg + (size_t)(row * 2) * CAP;
        unsigned* c1 = c0 + CAP;
        for (unsigned i = tid; i < n0; i += TPB) {
            unsigned p = gbase[0] + i; if (p < CAP) c0[p] = buf0[i];
        }
        for (unsigned i = tid; i < n1; i += TPB) {
            unsigned p = gbase[1] + i; if (p < CAP) c1[p] = buf1[i];
        }
    }
    grid.sync();

    // ================= P4: select (block = rq) =================
    {
        const int rq = bid;              // 256 blocks = 256 (row,quantile) pairs
        const int qrow = rq >> 1;
        const int iq   = rq & 1;
        unsigned* keys = smem;           // 4096
        unsigned* sh   = smem + CAP;     // 256
        unsigned m = gcnt[rq]; if (m > CAP) m = CAP;
        const unsigned* cand = candg + (size_t)rq * CAP;
        for (unsigned i = tid; i < m; i += TPB) keys[i] = cand[i];
        __syncthreads();
        const unsigned cb   = sbinfo[qrow * 8 + (iq ? 5 : 2)];
        const unsigned t_lo = (iq ? K_HI : K_LO) - cb;
        unsigned prefix = 0, trem = t_lo, cntEq = 0;
        for (int p = 3; p >= 0; --p) {
            if (tid < 256) sh[tid] = 0;
            __syncthreads();
            for (unsigned i = tid; i < m; i += TPB) {
                unsigned key = keys[i];
                bool match = (p == 3) || ((key >> ((p + 1) * 8)) == (prefix >> ((p + 1) * 8)));
                if (match) atomicAdd(&sh[(key >> (p * 8)) & 255u], 1u);
            }
            __syncthreads();
            if (tid == 0) {
                unsigned cum = 0;
                for (int b = 0; b < 256; ++b) {
                    unsigned c = sh[b];
                    if (trem >= cum && trem < cum + c) { svar[0] = (unsigned)b; svar[1] = cum; svar[2] = c; break; }
                    cum += c;
                }
            }
            __syncthreads();
            prefix |= svar[0] << (p * 8);
            trem   -= svar[1];
            cntEq   = svar[2];
            __syncthreads();
        }
        unsigned vlo_key = prefix;
        unsigned cntLess = t_lo - trem;
        unsigned vhi_key;
        if (t_lo + 1u < cntLess + cntEq) {
            vhi_key = vlo_key;           // duplicate covers rank t+1
        } else {
            if (tid == 0) svar[3] = 0xFFFFFFFFu;
            __syncthreads();
            for (unsigned i = tid; i < m; i += TPB) {
                unsigned key = keys[i];
                if (key > vlo_key) atomicMin(&svar[3], key);
            }
            __syncthreads();
            vhi_key = svar[3];
        }
        if (tid == 0) {
            double frac = iq ? (0.99 * (double)(NPR - 1) - (double)K_HI)
                             : (0.01 * (double)(NPR - 1) - (double)K_LO);
            double vlo = (double)keyToFloat(vlo_key);
            double vhi = (double)keyToFloat(vhi_key);
            qv[rq] = (float)(vlo + (vhi - vlo) * frac);
        }
    }
    grid.sync();

    // ================= P5: output (2 blocks/row) =================
    {
        float q0 = qv[row * 2], q1 = qv[row * 2 + 1];
        float a = alpha[0], bt = beta[0];
        float th = q0 + (q1 - q0) * a;
        bool  msk = th > 1e-14f;
        float thn = msk ? th : 1.0f;
        float thm = msk ? th : 0.0f;
        float nsc = -(bt / thn) * 1.4426950408889634f;   // -beta/th_new * log2(e)
        f32x4* ov = (f32x4*)(out + (size_t)row * NPR + (size_t)half * (NPR / 2));
        #pragma unroll 8
        for (int k = 0; k < 32; ++k) {
            int i = k * TPB + tid;
            float4 v = xr[i];
            f32x4 o;
            o.x = v.x > 0.f ? v.x * __builtin_amdgcn_rcpf(1.f + __builtin_amdgcn_exp2f(nsc * (fabsf(v.x) - thm))) : 0.f;
            o.y = v.y > 0.f ? v.y * __builtin_amdgcn_rcpf(1.f + __builtin_amdgcn_exp2f(nsc * (fabsf(v.y) - thm))) : 0.f;
            o.z = v.z > 0.f ? v.z * __builtin_amdgcn_rcpf(1.f + __builtin_amdgcn_exp2f(nsc * (fabsf(v.z) - thm))) : 0.f;
            o.w = v.w > 0.f ? v.w * __builtin_amdgcn_rcpf(1.f + __builtin_amdgcn_exp2f(nsc * (fabsf(v.w) - thm))) : 0.f;
            __builtin_nontemporal_store(o, &ov[i]);
        }
    }
}

extern "C" void kernel_launch(void* const* d_in, const int* in_sizes, int n_in,
                              void* d_out, int out_size, void* d_ws, size_t ws_size,
                              hipStream_t stream) {
    const float* x     = (const float*)d_in[0];
    const float* alpha = (const float*)d_in[1];
    const float* beta  = (const float*)d_in[2];
    float* out = (float*)d_out;
    unsigned* ws = (unsigned*)d_ws;
    unsigned* gh     = ws + OFF_GH;
    unsigned* sbinfo = ws + OFF_SB;
    unsigned* gcnt   = ws + OFF_GCNT;
    unsigned* candg  = ws + OFF_CAND;
    float*    qv     = (float*)(ws + OFF_QV);
    void* args[] = {(void*)&x, (void*)&alpha, (void*)&beta, (void*)&gh,
                    (void*)&sbinfo, (void*)&gcnt, (void*)&candg, (void*)&qv, (void*)&out};
    hipLaunchCooperativeKernel((const void*)k_fused, dim3(NBLK), dim3(TPB), args, 0, stream);
}